// Round 1
// baseline (412.605 us; speedup 1.0000x reference)
//
#include <hip/hip_runtime.h>
#include <hip/hip_bf16.h>
#include <math.h>

// Problem: B=64, T=2048, H=512, Q=512
// energies[b,t] = (W @ enc[b,t] + bias) . query[b]
//              = enc[b,t,:] . v[b,:] + c[b]
//   v[b,h] = sum_q query[b,q] * W[q,h]      (W is [Q,H] row-major)
//   c[b]   = sum_q query[b,q] * bias[q]
// softmax over t <= tgt_index[b]; context[b,:] = sum_t p[b,t] * enc[b,t,:]

#define B 64
#define T 2048
#define H 512
#define Q 512

// ---------------------------------------------------------------- kernel 1
// grid (B), block 512. v[b,h] and c[b].
__global__ void k_proj(const float* __restrict__ query,
                       const float* __restrict__ W,
                       const float* __restrict__ bias,
                       float* __restrict__ v,
                       float* __restrict__ c) {
    int b = blockIdx.x;
    int tid = threadIdx.x;  // 0..511, tid == h
    __shared__ float sq[Q];
    sq[tid] = query[(size_t)b * Q + tid];
    __syncthreads();

    float acc = 0.0f;
#pragma unroll 8
    for (int q = 0; q < Q; ++q) {
        acc += sq[q] * W[(size_t)q * H + tid];   // coalesced over tid
    }
    v[(size_t)b * H + tid] = acc;

    // c[b] = sum_q sq[q]*bias[q]
    float pb = sq[tid] * bias[tid];
    for (int off = 32; off; off >>= 1) pb += __shfl_xor(pb, off, 64);
    __shared__ float sred[8];
    if ((tid & 63) == 0) sred[tid >> 6] = pb;
    __syncthreads();
    if (tid == 0) {
        float s = 0.0f;
        for (int i = 0; i < 8; ++i) s += sred[i];
        c[b] = s;
    }
}

// ---------------------------------------------------------------- kernel 2
// grid (T/256, B), block 256 (4 waves). Wave-per-t, 512-elem dot via
// 2x float4 per lane + shuffle reduce. Only t < len is computed.
#define TT 256
__global__ void k_energy(const float* __restrict__ enc,
                         const float* __restrict__ v,
                         const float* __restrict__ c,
                         const int* __restrict__ tgt,
                         float* __restrict__ e) {
    int b = blockIdx.y;
    int len = tgt[b] + 1;
    int t0 = blockIdx.x * TT;
    if (t0 >= len) return;   // uniform exit, before any sync

    __shared__ float sv[H];
    int tid = threadIdx.x;
    sv[tid]       = v[(size_t)b * H + tid];
    sv[tid + 256] = v[(size_t)b * H + 256 + tid];
    __syncthreads();

    int wave = tid >> 6;
    int lane = tid & 63;
    float cb = c[b];
    const float4* sv4 = (const float4*)sv;
    float4 w0 = sv4[lane];
    float4 w1 = sv4[lane + 64];

    int tend = min(t0 + TT, len);
    for (int t = t0 + wave; t < tend; t += 4) {
        const float4* row = (const float4*)(enc + ((size_t)b * T + t) * H);
        float4 a0 = row[lane];
        float4 a1 = row[lane + 64];
        float acc = a0.x * w0.x + a0.y * w0.y + a0.z * w0.z + a0.w * w0.w
                  + a1.x * w1.x + a1.y * w1.y + a1.z * w1.z + a1.w * w1.w;
        for (int off = 32; off; off >>= 1) acc += __shfl_xor(acc, off, 64);
        if (lane == 0) e[(size_t)b * T + t] = acc + cb;
    }
}

// ---------------------------------------------------------------- kernel 3
// grid (B), block 256. Ragged softmax over t<len -> p[b,t] (normalized).
// Also zero-inits d_out (poisoned 0xAA) for kernel 4's atomics.
__global__ void k_softmax(const float* __restrict__ e,
                          const int* __restrict__ tgt,
                          float* __restrict__ p,
                          float* __restrict__ out) {
    int b = blockIdx.x;
    int len = tgt[b] + 1;
    int tid = threadIdx.x;  // 256

    out[(size_t)b * H + tid] = 0.0f;
    out[(size_t)b * H + 256 + tid] = 0.0f;

    __shared__ float red[256];

    float m = -INFINITY;
    for (int t = tid; t < len; t += 256) m = fmaxf(m, e[(size_t)b * T + t]);
    red[tid] = m;
    __syncthreads();
    for (int s = 128; s; s >>= 1) {
        if (tid < s) red[tid] = fmaxf(red[tid], red[tid + s]);
        __syncthreads();
    }
    m = red[0];
    __syncthreads();

    float s = 0.0f;
    for (int t = tid; t < len; t += 256) s += __expf(e[(size_t)b * T + t] - m);
    red[tid] = s;
    __syncthreads();
    for (int k = 128; k; k >>= 1) {
        if (tid < k) red[tid] += red[tid + k];
        __syncthreads();
    }
    float inv = 1.0f / red[0];

    for (int t = tid; t < len; t += 256)
        p[(size_t)b * T + t] = __expf(e[(size_t)b * T + t] - m) * inv;
}

// ---------------------------------------------------------------- kernel 4
// grid (T/256, B), block 256. Each block: 256-t chunk, p staged in LDS,
// thread owns h = {2*tid, 2*tid+1} via float2 coalesced loads.
// Accumulate into d_out with float atomics (zeroed by k_softmax).
__global__ void k_context(const float* __restrict__ enc,
                          const float* __restrict__ p,
                          const int* __restrict__ tgt,
                          float* __restrict__ out) {
    int b = blockIdx.y;
    int len = tgt[b] + 1;
    int t0 = blockIdx.x * TT;
    if (t0 >= len) return;   // uniform exit
    int n = min(TT, len - t0);

    __shared__ float sp[TT];
    int tid = threadIdx.x;
    sp[tid] = (tid < n) ? p[(size_t)b * T + t0 + tid] : 0.0f;
    __syncthreads();

    float acc0 = 0.0f, acc1 = 0.0f;
    const float* base = enc + ((size_t)b * T + t0) * H;

    int i = 0;
    for (; i + 4 <= n; i += 4) {
        const float2* r0 = (const float2*)(base + (size_t)(i + 0) * H);
        const float2* r1 = (const float2*)(base + (size_t)(i + 1) * H);
        const float2* r2 = (const float2*)(base + (size_t)(i + 2) * H);
        const float2* r3 = (const float2*)(base + (size_t)(i + 3) * H);
        float2 x0 = r0[tid];
        float2 x1 = r1[tid];
        float2 x2 = r2[tid];
        float2 x3 = r3[tid];
        float w0 = sp[i], w1 = sp[i + 1], w2 = sp[i + 2], w3 = sp[i + 3];
        acc0 += w0 * x0.x + w1 * x1.x + w2 * x2.x + w3 * x3.x;
        acc1 += w0 * x0.y + w1 * x1.y + w2 * x2.y + w3 * x3.y;
    }
    for (; i < n; ++i) {
        const float2* r = (const float2*)(base + (size_t)i * H);
        float2 x = r[tid];
        float w = sp[i];
        acc0 += w * x.x;
        acc1 += w * x.y;
    }

    atomicAdd(&out[(size_t)b * H + 2 * tid], acc0);
    atomicAdd(&out[(size_t)b * H + 2 * tid + 1], acc1);
}

// ---------------------------------------------------------------- launch
extern "C" void kernel_launch(void* const* d_in, const int* in_sizes, int n_in,
                              void* d_out, int out_size, void* d_ws, size_t ws_size,
                              hipStream_t stream) {
    const float* query = (const float*)d_in[0];   // [B,Q]
    const float* enc   = (const float*)d_in[1];   // [B,T,H]
    const float* W     = (const float*)d_in[2];   // [Q,H]
    const float* bias  = (const float*)d_in[3];   // [Q]
    const int*   tgt   = (const int*)d_in[4];     // [B]
    float* out = (float*)d_out;                   // [B,H]

    // workspace carve-up
    char* ws = (char*)d_ws;
    float* v = (float*)ws;                               ws += (size_t)B * H * sizeof(float);
    float* c = (float*)ws;                               ws += 256;  // B floats, padded
    float* e = (float*)ws;                               ws += (size_t)B * T * sizeof(float);
    float* p = (float*)ws;

    k_proj<<<dim3(B), dim3(512), 0, stream>>>(query, W, bias, v, c);
    k_energy<<<dim3(T / TT, B), dim3(256), 0, stream>>>(enc, v, c, tgt, e);
    k_softmax<<<dim3(B), dim3(256), 0, stream>>>(e, tgt, p, out);
    k_context<<<dim3(T / TT, B), dim3(256), 0, stream>>>(enc, p, tgt, out);
}

// Round 2
// 392.262 us; speedup vs baseline: 1.0519x; 1.0519x over previous
//
#include <hip/hip_runtime.h>
#include <hip/hip_bf16.h>
#include <math.h>

// B=64, T=2048, H=512, Q=512
// energies[b,t] = enc[b,t,:] . v[b,:] + c[b]
//   v[b,h] = sum_q query[b,q] * W[q,h]   (W row-major [Q,H])
//   c[b]   = query[b,:] . bias
// softmax over t < len=tgt[b]+1; context[b,:] = sum_t p[b,t] * enc[b,t,:]
//
// Fused single-pass: per-wave online softmax, enc read EXACTLY ONCE from HBM.
// Wave-per-row: lane l holds row elements h = {4l..4l+3} and {256+4l..256+4l+3}
// (two float4 loads) — the same h's it accumulates context for. Per-wave
// partials (m, l, ctx[512]) -> ws; combine kernel merges and writes out.

#define B 64
#define T 2048
#define H 512
#define Q 512
#define TT 128          // rows per block-chunk
#define NCH (T / TT)    // 16 chunks per batch
#define NPW (NCH * 4)   // 64 wave-partials per batch (4 waves/block)

// ---------------------------------------------------------------- kernel 1
// v[b,h], c[b].  grid (H/128, B), block 128.
__global__ void k_proj(const float* __restrict__ query,
                       const float* __restrict__ W,
                       const float* __restrict__ bias,
                       float* __restrict__ v,
                       float* __restrict__ c) {
    int b = blockIdx.y;
    int tid = threadIdx.x;           // 0..127
    int h = blockIdx.x * 128 + tid;

    __shared__ float sq[Q];
    for (int i = tid; i < Q; i += 128) sq[i] = query[(size_t)b * Q + i];
    __syncthreads();

    float acc = 0.0f;
#pragma unroll 8
    for (int q = 0; q < Q; ++q) acc += sq[q] * W[(size_t)q * H + h];
    v[(size_t)b * H + h] = acc;

    if (blockIdx.x == 0) {
        float pb = 0.0f;
        for (int i = tid; i < Q; i += 128) pb += sq[i] * bias[i];
        for (int off = 32; off; off >>= 1) pb += __shfl_xor(pb, off, 64);
        __shared__ float sred[2];
        if ((tid & 63) == 0) sred[tid >> 6] = pb;
        __syncthreads();
        if (tid == 0) c[b] = sred[0] + sred[1];
    }
}

// ---------------------------------------------------------------- kernel 2
// Fused energy + online-softmax + context partial.
// grid (NCH, B), block 256 (4 waves). Wave w handles rows t0+w, t0+w+4, ...
__global__ __launch_bounds__(256) void k_attn(const float* __restrict__ enc,
                                              const float* __restrict__ v,
                                              const float* __restrict__ c,
                                              const int* __restrict__ tgt,
                                              float* __restrict__ pm,
                                              float* __restrict__ pl,
                                              float* __restrict__ pctx) {
    int b = blockIdx.y;
    int len = tgt[b] + 1;
    int t0 = blockIdx.x * TT;
    if (t0 >= len) return;           // uniform exit, before any sync
    int n = min(TT, len - t0);

    __shared__ float sv[H];
    int tid = threadIdx.x;
    sv[tid]       = v[(size_t)b * H + tid];
    sv[tid + 256] = v[(size_t)b * H + 256 + tid];
    __syncthreads();

    int wave = tid >> 6;
    int lane = tid & 63;
    const float4* sv4 = (const float4*)sv;
    float4 w0 = sv4[lane];
    float4 w1 = sv4[lane + 64];
    float cb = c[b];

    float m = -INFINITY, l = 0.0f;
    float4 a0 = {0.f, 0.f, 0.f, 0.f};
    float4 a1 = {0.f, 0.f, 0.f, 0.f};

    for (int t = wave; t < n; t += 4) {
        const float4* row = (const float4*)(enc + ((size_t)b * T + t0 + t) * H);
        float4 x0 = row[lane];
        float4 x1 = row[lane + 64];
        float e = x0.x * w0.x + x0.y * w0.y + x0.z * w0.z + x0.w * w0.w
                + x1.x * w1.x + x1.y * w1.y + x1.z * w1.z + x1.w * w1.w;
        for (int off = 32; off; off >>= 1) e += __shfl_xor(e, off, 64);
        e += cb;

        float mn = fmaxf(m, e);
        float alpha = __expf(m - mn);     // m=-inf first iter -> alpha=0
        float p = __expf(e - mn);
        l = l * alpha + p;
        a0.x = a0.x * alpha + p * x0.x;
        a0.y = a0.y * alpha + p * x0.y;
        a0.z = a0.z * alpha + p * x0.z;
        a0.w = a0.w * alpha + p * x0.w;
        a1.x = a1.x * alpha + p * x1.x;
        a1.y = a1.y * alpha + p * x1.y;
        a1.z = a1.z * alpha + p * x1.z;
        a1.w = a1.w * alpha + p * x1.w;
        m = mn;
    }

    // per-wave partial out (waves with zero rows write m=-inf, l=0, ctx=0)
    int pidx = (b * NCH + blockIdx.x) * 4 + wave;
    if (lane == 0) { pm[pidx] = m; pl[pidx] = l; }
    float4* dst = (float4*)(pctx + (size_t)pidx * H);
    dst[lane]      = a0;
    dst[lane + 64] = a1;
}

// ---------------------------------------------------------------- kernel 3
// Merge per-wave partials; write final out (full overwrite, no init needed).
// grid (B), block 256. Thread owns h = {2*tid, 2*tid+1}.
__global__ void k_combine(const float* __restrict__ pm,
                          const float* __restrict__ pl,
                          const float* __restrict__ pctx,
                          const int* __restrict__ tgt,
                          float* __restrict__ out) {
    int b = blockIdx.x;
    int len = tgt[b] + 1;
    int nch = (len + TT - 1) / TT;
    int np = nch * 4;
    int base = b * NPW;
    int tid = threadIdx.x;

    float M = -INFINITY;
    for (int j = 0; j < np; ++j) M = fmaxf(M, pm[base + j]);
    float L = 0.0f;
    for (int j = 0; j < np; ++j) L += pl[base + j] * __expf(pm[base + j] - M);
    float invL = 1.0f / L;

    float acc0 = 0.0f, acc1 = 0.0f;
    for (int j = 0; j < np; ++j) {
        float mj = pm[base + j];
        float w = (mj == -INFINITY) ? 0.0f : __expf(mj - M) * invL;
        const float2* pc = (const float2*)(pctx + (size_t)(base + j) * H);
        float2 x = pc[tid];
        acc0 += w * x.x;
        acc1 += w * x.y;
    }
    out[(size_t)b * H + 2 * tid]     = acc0;
    out[(size_t)b * H + 2 * tid + 1] = acc1;
}

// ---------------------------------------------------------------- launch
extern "C" void kernel_launch(void* const* d_in, const int* in_sizes, int n_in,
                              void* d_out, int out_size, void* d_ws, size_t ws_size,
                              hipStream_t stream) {
    const float* query = (const float*)d_in[0];   // [B,Q]
    const float* enc   = (const float*)d_in[1];   // [B,T,H]
    const float* W     = (const float*)d_in[2];   // [Q,H]
    const float* bias  = (const float*)d_in[3];   // [Q]
    const int*   tgt   = (const int*)d_in[4];     // [B]
    float* out = (float*)d_out;                   // [B,H]

    char* ws = (char*)d_ws;
    float* v    = (float*)ws;  ws += (size_t)B * H * sizeof(float);
    float* c    = (float*)ws;  ws += 256;
    float* pm   = (float*)ws;  ws += (size_t)B * NPW * sizeof(float);
    float* pl   = (float*)ws;  ws += (size_t)B * NPW * sizeof(float);
    float* pctx = (float*)ws;  // B * NPW * H floats = 8 MB

    k_proj<<<dim3(H / 128, B), dim3(128), 0, stream>>>(query, W, bias, v, c);
    k_attn<<<dim3(NCH, B), dim3(256), 0, stream>>>(enc, v, c, tgt, pm, pl, pctx);
    k_combine<<<dim3(B), dim3(256), 0, stream>>>(pm, pl, pctx, tgt, out);
}